// Round 16
// baseline (144.524 us; speedup 1.0000x reference)
//
#include <hip/hip_runtime.h>
#include <hip/hip_fp16.h>

typedef unsigned short u16;
typedef __attribute__((ext_vector_type(8))) short short8;
typedef __attribute__((ext_vector_type(4))) float f32x4;
typedef __attribute__((ext_vector_type(4))) unsigned short u16x4;
typedef __attribute__((ext_vector_type(4))) float float4v;

__device__ __forceinline__ u16 f2bf(float f) {
  union { float f; unsigned u; } v; v.f = f;
  unsigned r = v.u + 0x7FFFu + ((v.u >> 16) & 1u);
  return (u16)(r >> 16);
}

__device__ __forceinline__ u16 f2h(float f) {
  __half h = __float2half(f);
  return *reinterpret_cast<u16*>(&h);
}

__device__ __forceinline__ float h2f(u16 b) {
  __half_raw hr; hr.x = b;
  return __half2float(__half(hr));
}

__device__ __forceinline__ void gload16(const void* g, void* l) {
  __builtin_amdgcn_global_load_lds(
      (const __attribute__((address_space(1))) unsigned int*)g,
      (__attribute__((address_space(3))) unsigned int*)l, 16, 0, 0);
}

// ---- fp32->bf16 staging for BOTH panels with full load ILP ----
// Issues all 16 float4 loads (8 per panel) before any use -> one vmcnt wait
// per K-iter instead of 8 serialized HBM round-trips. Same swizzle as
// stage64: LDS dest slot d of row r holds global slot d^(r&7).
__device__ __forceinline__ void stageAB_f32(const float* __restrict__ ga,
                                            const float* __restrict__ gb,
                                            int k0, u16* As, u16* Bs, int t) {
  float4v va[4][2], vb[4][2];
#pragma unroll
  for (int j = 0; j < 4; ++j) {
    const int o = (j * 256 + t) * 8;    // u16 offset in [128][64]
    const int row = o >> 6;
    const int gslot = ((o >> 3) & 7) ^ (row & 7);
    const float* sa = ga + (size_t)row * 1024 + k0 + gslot * 8;
    const float* sb = gb + (size_t)row * 1024 + k0 + gslot * 8;
    va[j][0] = *(const float4v*)sa;
    va[j][1] = *(const float4v*)(sa + 4);
    vb[j][0] = *(const float4v*)sb;
    vb[j][1] = *(const float4v*)(sb + 4);
  }
#pragma unroll
  for (int j = 0; j < 4; ++j) {
    const int o = (j * 256 + t) * 8;
    short8 wa, wb;
    wa[0] = (short)f2bf(va[j][0].x); wa[1] = (short)f2bf(va[j][0].y);
    wa[2] = (short)f2bf(va[j][0].z); wa[3] = (short)f2bf(va[j][0].w);
    wa[4] = (short)f2bf(va[j][1].x); wa[5] = (short)f2bf(va[j][1].y);
    wa[6] = (short)f2bf(va[j][1].z); wa[7] = (short)f2bf(va[j][1].w);
    wb[0] = (short)f2bf(vb[j][0].x); wb[1] = (short)f2bf(vb[j][0].y);
    wb[2] = (short)f2bf(vb[j][0].z); wb[3] = (short)f2bf(vb[j][0].w);
    wb[4] = (short)f2bf(vb[j][1].x); wb[5] = (short)f2bf(vb[j][1].y);
    wb[6] = (short)f2bf(vb[j][1].z); wb[7] = (short)f2bf(vb[j][1].w);
    *(short8*)(As + o) = wa;
    *(short8*)(Bs + o) = wb;
  }
}

// ---------------- merged conversion + Mt kernel ----------------
// bx<64: Mt = (Wk Wq^T)/32 GEMM straight from fp32 weights (starts first,
// overlaps the conversion blocks).  +1024: Wv transpose.  rest: X convert.
__global__ __launch_bounds__(256) void kconv(const float* __restrict__ X,
                                             const float* __restrict__ Wq,
                                             const float* __restrict__ Wk,
                                             const float* __restrict__ Wv,
                                             u16* __restrict__ Xb,
                                             u16* __restrict__ Wvt,
                                             u16* __restrict__ Mt) {
  __shared__ __align__(16) u16 sm[2][128 * 64];
  const int bx = blockIdx.x;
  const int t = threadIdx.x;
  if (bx < 64) {
    u16* As = sm[0];
    u16* Bs = sm[1];
    const f32x4 z4 = {0.f, 0.f, 0.f, 0.f};
    f32x4 acc[4][4];
#pragma unroll
    for (int i = 0; i < 4; i++)
#pragma unroll
      for (int j = 0; j < 4; j++) acc[i][j] = z4;

    const int rowBase = (bx >> 3) * 128, colBase = (bx & 7) * 128;
    const float* ga = Wk + (size_t)rowBase * 1024;
    const float* gb = Wq + (size_t)colBase * 1024;
    const int wid = t >> 6, lane = t & 63;
    const int wm = wid >> 1, wn = wid & 1;
    const int l15 = lane & 15;
    const int sw = l15 & 7;
    const int sl = lane >> 4;
    const int s0 = ((sl) ^ sw) * 8;
    const int s1 = ((sl + 4) ^ sw) * 8;

    for (int kt = 0; kt < 16; ++kt) {
      const int k0 = kt * 64;
      stageAB_f32(ga, gb, k0, As, Bs, t);
      __syncthreads();
#pragma unroll
      for (int h = 0; h < 2; ++h) {
        const int so = h ? s1 : s0;
        short8 a[4], b[4];
#pragma unroll
        for (int mi = 0; mi < 4; mi++)
          a[mi] = *(const short8*)(As + (wm * 64 + mi * 16 + l15) * 64 + so);
#pragma unroll
        for (int ni = 0; ni < 4; ni++)
          b[ni] = *(const short8*)(Bs + (wn * 64 + ni * 16 + l15) * 64 + so);
#pragma unroll
        for (int mi = 0; mi < 4; mi++)
#pragma unroll
          for (int ni = 0; ni < 4; ni++)
            acc[mi][ni] = __builtin_amdgcn_mfma_f32_16x16x32_bf16(
                a[mi], b[ni], acc[mi][ni], 0, 0, 0);
      }
      __syncthreads();
    }

    const int r0 = rowBase + wm * 64 + ((lane >> 4) * 4);
    const int c0 = colBase + wn * 64 + l15;
#pragma unroll
    for (int mi = 0; mi < 4; mi++) {
      int r = r0 + mi * 16;
#pragma unroll
      for (int ni = 0; ni < 4; ni++) {
        int c = c0 + ni * 16;
#pragma unroll
        for (int j = 0; j < 4; j++)
          Mt[(size_t)(r + j) * 1024 + c] = f2bf(acc[mi][ni][j] * 0.03125f);
      }
    }
  } else if (bx < 1088) {
    float* tile = (float*)sm;           // [32][33]
    const int rem = bx - 64;            // 32x32 tiles of Wv
    const int n0 = (rem & 31) * 32, k0 = (rem >> 5) * 32;
    const int tx = t & 31, ty = t >> 5; // 32 x 8
#pragma unroll
    for (int r = 0; r < 32; r += 8)
      tile[(ty + r) * 33 + tx] = Wv[(size_t)(k0 + ty + r) * 1024 + n0 + tx];
    __syncthreads();
#pragma unroll
    for (int r = 0; r < 32; r += 8)
      Wvt[(size_t)(n0 + ty + r) * 1024 + k0 + tx] = f2bf(tile[tx * 33 + ty + r]);
  } else {
    const int l = bx - 1088;            // 0..8191
    size_t i = ((size_t)l * 256 + t) * 4;
    float4v v = *(const float4v*)(X + i);
    u16x4 o;
    o.x = f2bf(v.x); o.y = f2bf(v.y); o.z = f2bf(v.z); o.w = f2bf(v.w);
    *(u16x4*)(Xb + i) = o;
  }
}

// ---------------- GEMM core: BK=64, both-sides XOR swizzle ----------------
__device__ __forceinline__ void stage64(const u16* __restrict__ pan, int ld,
                                        int k0, u16* dst, int t) {
  const int rb = t >> 3;                     // 0..31
  const int sw = ((t & 7) ^ (rb & 7)) * 8;   // pre-swizzled source slot
  const int ds = (t & 7) * 8;                // linear LDS slot
#pragma unroll
  for (int j = 0; j < 4; ++j) {
    const int row = j * 32 + rb;
    gload16(pan + (size_t)row * ld + k0 + sw, dst + row * 64 + ds);
  }
}

__device__ __forceinline__ void gemm64(const u16* __restrict__ A,
                                       const u16* __restrict__ B,
                                       int lda, int ldb,
                                       int rowBase, int colBase, int kIters,
                                       u16* As, u16* Bs, f32x4 acc[4][4]) {
  const int t = threadIdx.x;
  const int wid = t >> 6, lane = t & 63;
  const int wm = wid >> 1, wn = wid & 1;
  const int l15 = lane & 15;
  const int sw = l15 & 7;
  const int sl = lane >> 4;                  // 0..3
  const int s0 = ((sl    ) ^ sw) * 8;        // k 0..31 slot (u16 offset)
  const int s1 = ((sl + 4) ^ sw) * 8;        // k 32..63 slot
  const u16* ga = A + (size_t)rowBase * lda;
  const u16* gb = B + (size_t)colBase * ldb;

  for (int kt = 0; kt < kIters; ++kt) {
    const int k0 = kt * 64;
    stage64(ga, lda, k0, As, t);
    stage64(gb, ldb, k0, Bs, t);
    __syncthreads();
#pragma unroll
    for (int h = 0; h < 2; ++h) {
      const int so = h ? s1 : s0;
      short8 a[4], b[4];
#pragma unroll
      for (int mi = 0; mi < 4; mi++)
        a[mi] = *(const short8*)(As + (wm * 64 + mi * 16 + l15) * 64 + so);
#pragma unroll
      for (int ni = 0; ni < 4; ni++)
        b[ni] = *(const short8*)(Bs + (wn * 64 + ni * 16 + l15) * 64 + so);
#pragma unroll
      for (int mi = 0; mi < 4; mi++)
#pragma unroll
        for (int ni = 0; ni < 4; ni++)
          acc[mi][ni] = __builtin_amdgcn_mfma_f32_16x16x32_bf16(
              a[mi], b[ni], acc[mi][ni], 0, 0, 0);
    }
    __syncthreads();
  }
}

// ---------------- Q' = X Mt^T  and  V (transposed) ----------------
// 1024 blocks at 4/CU (one resident round). XCD-chunked rows.
__global__ __launch_bounds__(256, 4) void kqkv(const u16* __restrict__ Xb,
                                               const u16* __restrict__ Mt,
                                               const u16* __restrict__ Wvt,
                                               u16* __restrict__ Qb,
                                               u16* __restrict__ Vt) {
  __shared__ __align__(16) u16 As[128 * 64];
  __shared__ __align__(16) u16 Bs[128 * 64];
  const f32x4 z4 = {0.f, 0.f, 0.f, 0.f};
  f32x4 acc[4][4];
#pragma unroll
  for (int i = 0; i < 4; i++)
#pragma unroll
    for (int j = 0; j < 4; j++) acc[i][j] = z4;

  const int l = blockIdx.x;
  const int xcd = l & 7, idx = l >> 3;     // idx 0..127
  const int cz = idx >> 3, rloc = idx & 7; // cz 0..15 outer, row inner
  const int rowTile = xcd * 8 + rloc;      // 0..63
  const int z = cz >> 3, colTile = cz & 7; // z 0..1, col 0..7

  const int rowBase = rowTile * 128, colBase = colTile * 128;
  const u16* Bt = z ? Wvt : Mt;
  gemm64(Xb, Bt, 1024, 1024, rowBase, colBase, 16, As, Bs, acc);

  const int t = threadIdx.x, wid = t >> 6, lane = t & 63;
  const int wm = wid >> 1, wn = wid & 1;
  const int r0 = rowBase + wm * 64 + ((lane >> 4) * 4);
  const int c0 = colBase + wn * 64 + (lane & 15);
  if (z == 0) {
#pragma unroll
    for (int mi = 0; mi < 4; mi++) {
      int r = r0 + mi * 16;
#pragma unroll
      for (int ni = 0; ni < 4; ni++) {
        int c = c0 + ni * 16;
#pragma unroll
        for (int j = 0; j < 4; j++)
          Qb[(size_t)(r + j) * 1024 + c] = f2bf(acc[mi][ni][j]);
      }
    }
  } else {
#pragma unroll
    for (int mi = 0; mi < 4; mi++) {
      int s0r = r0 + mi * 16;           // global row (= b*2048 + s)
      int bb = s0r >> 11, sl = s0r & 2047;
#pragma unroll
      for (int ni = 0; ni < 4; ni++) {
        int d = c0 + ni * 16;
        u16x4 pk;
        pk.x = f2bf(acc[mi][ni][0]);
        pk.y = f2bf(acc[mi][ni][1]);
        pk.z = f2bf(acc[mi][ni][2]);
        pk.w = f2bf(acc[mi][ni][3]);
        *(u16x4*)(Vt + ((size_t)bb * 1024 + d) * 2048 + sl) = pk;
      }
    }
  }
}

// -------- scores = Q' X^T (already /32 via Mt), lower-tri, fp16 out --------
__global__ __launch_bounds__(256, 3) void kscores(const u16* __restrict__ Q,
                                                  const u16* __restrict__ Xb,
                                                  u16* __restrict__ Sch) {
  const int x = blockIdx.x, b = blockIdx.y;
  const int xcd = x & 7, idx = x >> 3;   // idx 0..16
  const int tid = xcd * 17 + idx;        // 0..135
  int tr = (int)((sqrtf(8.f * tid + 1.f) - 1.f) * 0.5f);
  while ((tr + 1) * (tr + 2) / 2 <= tid) ++tr;
  while (tr * (tr + 1) / 2 > tid) --tr;
  const int tc = tid - tr * (tr + 1) / 2;

  __shared__ __align__(16) u16 As[128 * 64];
  __shared__ __align__(16) u16 Bs[128 * 64];
  const f32x4 z4 = {0.f, 0.f, 0.f, 0.f};
  f32x4 acc[4][4];
#pragma unroll
  for (int i = 0; i < 4; i++)
#pragma unroll
    for (int j = 0; j < 4; j++) acc[i][j] = z4;

  const u16* Qp = Q + (size_t)b * 2048 * 1024;
  const u16* Kp = Xb + (size_t)b * 2048 * 1024;   // B-panel is X itself
  gemm64(Qp, Kp, 1024, 1024, tr * 128, tc * 128, 16, As, Bs, acc);

  u16* S = Sch + (size_t)b * 2048 * 2048;
  const int t = threadIdx.x, wid = t >> 6, lane = t & 63;
  const int wm = wid >> 1, wn = wid & 1;
  const int r0 = tr * 128 + wm * 64 + ((lane >> 4) * 4);
  const int c0 = tc * 128 + wn * 64 + (lane & 15);
#pragma unroll
  for (int mi = 0; mi < 4; mi++) {
    int r = r0 + mi * 16;
#pragma unroll
    for (int ni = 0; ni < 4; ni++) {
      int c = c0 + ni * 16;
#pragma unroll
      for (int j = 0; j < 4; j++)
        S[(size_t)(r + j) * 2048 + c] = f2h(acc[mi][ni][j]);
    }
  }
}

// ---------------- row softmax (register-resident, nceil-bounded) ------------
__global__ __launch_bounds__(256) void ksoftmax(const u16* __restrict__ Sch,
                                                u16* __restrict__ P) {
  const int i = blockIdx.x, b = blockIdx.y;
  const int t = threadIdx.x, lane = t & 63, wid = t >> 6;
  const int nceil = ((i >> 7) + 1) << 7;
  __shared__ float red[4];

  const size_t rowoff = ((size_t)b * 2048 + i) * 2048 + t * 8;
  const int base = t * 8;
  short8 raw = {0, 0, 0, 0, 0, 0, 0, 0};
  if (base < nceil) raw = *(const short8*)(Sch + rowoff);
  float v[8];
#pragma unroll
  for (int k = 0; k < 8; ++k)
    v[k] = (base + k <= i) ? h2f((u16)raw[k]) : -3.0e38f;

  float lm = v[0];
#pragma unroll
  for (int k = 1; k < 8; ++k) lm = fmaxf(lm, v[k]);
#pragma unroll
  for (int o = 32; o > 0; o >>= 1) lm = fmaxf(lm, __shfl_down(lm, o));
  if (lane == 0) red[wid] = lm;
  __syncthreads();
  const float m = fmaxf(fmaxf(red[0], red[1]), fmaxf(red[2], red[3]));
  __syncthreads();  // everyone has m before red[] is reused

  float e[8], ls = 0.f;
#pragma unroll
  for (int k = 0; k < 8; ++k) {
    e[k] = __expf(fmaxf(v[k] - m, -88.f));
    ls += e[k];
  }
#pragma unroll
  for (int o = 32; o > 0; o >>= 1) ls += __shfl_down(ls, o);
  if (lane == 0) red[wid] = ls;
  __syncthreads();
  const float inv = 1.f / (red[0] + red[1] + red[2] + red[3]);

  if (base < nceil) {
    short8 out;
#pragma unroll
    for (int k = 0; k < 8; ++k) out[k] = (short)f2bf(e[k] * inv);
    *(short8*)(P + rowoff) = out;
  }
}

// ---------------- context = P V  (K-loop truncated causally) ----------------
__global__ __launch_bounds__(256, 3) void kpv(const u16* __restrict__ P,
                                              const u16* __restrict__ Vt,
                                              float* __restrict__ Out) {
  const int x = blockIdx.x, b = blockIdx.y;
  const int xcd = x & 7, idx = x >> 3;       // idx 0..15
  const int tr = (idx & 1) ? (15 - xcd) : xcd;
  const int col = idx >> 1;                  // 0..7

  __shared__ __align__(16) u16 As[128 * 64];
  __shared__ __align__(16) u16 Bs[128 * 64];
  const f32x4 z4 = {0.f, 0.f, 0.f, 0.f};
  f32x4 acc[4][4];
#pragma unroll
  for (int i = 0; i < 4; i++)
#pragma unroll
    for (int j = 0; j < 4; j++) acc[i][j] = z4;

  const u16* Pp = P + (size_t)b * 2048 * 2048;
  const u16* Vp = Vt + (size_t)b * 1024 * 2048;
  gemm64(Pp, Vp, 2048, 2048, tr * 128, col * 128, (tr + 1) * 2, As, Bs, acc);

  float* Ob = Out + (size_t)b * 2048 * 1024;
  const int t = threadIdx.x, wid = t >> 6, lane = t & 63;
  const int wm = wid >> 1, wn = wid & 1;
  const int r0 = tr * 128 + wm * 64 + ((lane >> 4) * 4);
  const int c0 = col * 128 + wn * 64 + (lane & 15);
#pragma unroll
  for (int mi = 0; mi < 4; mi++) {
    int r = r0 + mi * 16;
#pragma unroll
    for (int ni = 0; ni < 4; ni++) {
      int c = c0 + ni * 16;
#pragma unroll
      for (int j = 0; j < 4; j++)
        Ob[(size_t)(r + j) * 1024 + c] = acc[mi][ni][j];
    }
  }
}

extern "C" void kernel_launch(void* const* d_in, const int* in_sizes, int n_in,
                              void* d_out, int out_size, void* d_ws,
                              size_t ws_size, hipStream_t stream) {
  const float* X = (const float*)d_in[0];
  const float* Wq = (const float*)d_in[1];
  const float* Wk = (const float*)d_in[2];
  const float* Wv = (const float*)d_in[3];
  float* Out = (float*)d_out;

  char* ws = (char*)d_ws;
  u16* Xb  = (u16*)(ws);                    // 16 MB  bf16 X
  u16* Wvt = (u16*)(ws + 16777216);         //  2 MB  bf16 Wv^T
  u16* Mt  = (u16*)(ws + 18874368);         //  2 MB  bf16 (Wk Wq^T)/32
  u16* Qb  = (u16*)(ws + 20971520);         // 16 MB  Q' = X Mt^T
  u16* Vt  = (u16*)(ws + 37748736);         // 16 MB  V transposed per batch
  u16* Sch = (u16*)(ws + 54525952);         // 32 MB  fp16 scores
  u16* P   = (u16*)(ws + 88080384);         // 32 MB  bf16 probs

  kconv<<<9280, 256, 0, stream>>>(X, Wq, Wk, Wv, Xb, Wvt, Mt);
  kqkv<<<1024, 256, 0, stream>>>(Xb, Mt, Wvt, Qb, Vt);
  kscores<<<dim3(136, 4), 256, 0, stream>>>(Qb, Xb, Sch);
  ksoftmax<<<dim3(2048, 4), 256, 0, stream>>>(Sch, P);
  kpv<<<dim3(128, 4), 256, 0, stream>>>(P, Vt, Out);
}

// Round 18
// 140.028 us; speedup vs baseline: 1.0321x; 1.0321x over previous
//
#include <hip/hip_runtime.h>
#include <hip/hip_fp16.h>

typedef unsigned short u16;
typedef __attribute__((ext_vector_type(8))) short short8;
typedef __attribute__((ext_vector_type(4))) float f32x4;
typedef __attribute__((ext_vector_type(4))) unsigned short u16x4;
typedef __attribute__((ext_vector_type(4))) float float4v;

__device__ __forceinline__ u16 f2bf(float f) {
  union { float f; unsigned u; } v; v.f = f;
  unsigned r = v.u + 0x7FFFu + ((v.u >> 16) & 1u);
  return (u16)(r >> 16);
}

__device__ __forceinline__ u16 f2h(float f) {
  __half h = __float2half(f);
  return *reinterpret_cast<u16*>(&h);
}

__device__ __forceinline__ float h2f(u16 b) {
  __half_raw hr; hr.x = b;
  return __half2float(__half(hr));
}

__device__ __forceinline__ void gload16(const void* g, void* l) {
  __builtin_amdgcn_global_load_lds(
      (const __attribute__((address_space(1))) unsigned int*)g,
      (__attribute__((address_space(3))) unsigned int*)l, 16, 0, 0);
}

// ---------------- stage 1: weight conversions (pure BW, ~3 us) ----------------
// bx<1024: Wq fp32->bf16 linear.  <2048: Wk linear.  else: Wv transpose.
__global__ __launch_bounds__(256) void kconvW(const float* __restrict__ Wq,
                                              const float* __restrict__ Wk,
                                              const float* __restrict__ Wv,
                                              u16* __restrict__ Wqb,
                                              u16* __restrict__ Wkb,
                                              u16* __restrict__ Wvt) {
  __shared__ float tile[32][33];
  const int bx = blockIdx.x, t = threadIdx.x;
  if (bx < 2048) {
    const float* W = bx < 1024 ? Wq : Wk;
    u16* O = bx < 1024 ? Wqb : Wkb;
    size_t i = ((size_t)(bx & 1023) * 256 + t) * 4;
    float4v v = *(const float4v*)(W + i);
    u16x4 o;
    o.x = f2bf(v.x); o.y = f2bf(v.y); o.z = f2bf(v.z); o.w = f2bf(v.w);
    *(u16x4*)(O + i) = o;
  } else {
    const int rem = bx - 2048;          // 32x32 tiles of Wv
    const int n0 = (rem & 31) * 32, k0 = (rem >> 5) * 32;
    const int tx = t & 31, ty = t >> 5; // 32 x 8
#pragma unroll
    for (int r = 0; r < 32; r += 8)
      tile[ty + r][tx] = Wv[(size_t)(k0 + ty + r) * 1024 + n0 + tx];
    __syncthreads();
#pragma unroll
    for (int r = 0; r < 32; r += 8)
      Wvt[(size_t)(n0 + ty + r) * 1024 + k0 + tx] = f2bf(tile[tx][ty + r]);
  }
}

// ---------------- GEMM core: BK=64, both-sides XOR swizzle ----------------
__device__ __forceinline__ void stage64(const u16* __restrict__ pan, int ld,
                                        int k0, u16* dst, int t) {
  const int rb = t >> 3;                     // 0..31
  const int sw = ((t & 7) ^ (rb & 7)) * 8;   // pre-swizzled source slot
  const int ds = (t & 7) * 8;                // linear LDS slot
#pragma unroll
  for (int j = 0; j < 4; ++j) {
    const int row = j * 32 + rb;
    gload16(pan + (size_t)row * ld + k0 + sw, dst + row * 64 + ds);
  }
}

__device__ __forceinline__ void gemm64(const u16* __restrict__ A,
                                       const u16* __restrict__ B,
                                       int lda, int ldb,
                                       int rowBase, int colBase, int kIters,
                                       u16* As, u16* Bs, f32x4 acc[4][4]) {
  const int t = threadIdx.x;
  const int wid = t >> 6, lane = t & 63;
  const int wm = wid >> 1, wn = wid & 1;
  const int l15 = lane & 15;
  const int sw = l15 & 7;
  const int sl = lane >> 4;                  // 0..3
  const int s0 = ((sl    ) ^ sw) * 8;        // k 0..31 slot (u16 offset)
  const int s1 = ((sl + 4) ^ sw) * 8;        // k 32..63 slot
  const u16* ga = A + (size_t)rowBase * lda;
  const u16* gb = B + (size_t)colBase * ldb;

  for (int kt = 0; kt < kIters; ++kt) {
    const int k0 = kt * 64;
    stage64(ga, lda, k0, As, t);
    stage64(gb, ldb, k0, Bs, t);
    __syncthreads();
#pragma unroll
    for (int h = 0; h < 2; ++h) {
      const int so = h ? s1 : s0;
      short8 a[4], b[4];
#pragma unroll
      for (int mi = 0; mi < 4; mi++)
        a[mi] = *(const short8*)(As + (wm * 64 + mi * 16 + l15) * 64 + so);
#pragma unroll
      for (int ni = 0; ni < 4; ni++)
        b[ni] = *(const short8*)(Bs + (wn * 64 + ni * 16 + l15) * 64 + so);
#pragma unroll
      for (int mi = 0; mi < 4; mi++)
#pragma unroll
        for (int ni = 0; ni < 4; ni++)
          acc[mi][ni] = __builtin_amdgcn_mfma_f32_16x16x32_bf16(
              a[mi], b[ni], acc[mi][ni], 0, 0, 0);
    }
    __syncthreads();
  }
}

// ---------------- stage 2: X convert + Mt GEMM (overlapped) ----------------
// bx<64: Mt = (Wk Wq^T)/32 from bf16 via gload_lds (runs ~10us, hidden under
// the 8192 X-convert blocks).  else: X fp32->bf16 linear.
__global__ __launch_bounds__(256) void kconvX(const float* __restrict__ X,
                                              const u16* __restrict__ Wqb,
                                              const u16* __restrict__ Wkb,
                                              u16* __restrict__ Xb,
                                              u16* __restrict__ Mt) {
  __shared__ __align__(16) u16 As[128 * 64];
  __shared__ __align__(16) u16 Bs[128 * 64];
  const int bx = blockIdx.x, t = threadIdx.x;
  if (bx < 64) {
    const f32x4 z4 = {0.f, 0.f, 0.f, 0.f};
    f32x4 acc[4][4];
#pragma unroll
    for (int i = 0; i < 4; i++)
#pragma unroll
      for (int j = 0; j < 4; j++) acc[i][j] = z4;

    const int rowBase = (bx >> 3) * 128, colBase = (bx & 7) * 128;
    gemm64(Wkb, Wqb, 1024, 1024, rowBase, colBase, 16, As, Bs, acc);

    const int wid = t >> 6, lane = t & 63;
    const int wm = wid >> 1, wn = wid & 1;
    const int r0 = rowBase + wm * 64 + ((lane >> 4) * 4);
    const int c0 = colBase + wn * 64 + (lane & 15);
#pragma unroll
    for (int mi = 0; mi < 4; mi++) {
      int r = r0 + mi * 16;
#pragma unroll
      for (int ni = 0; ni < 4; ni++) {
        int c = c0 + ni * 16;
#pragma unroll
        for (int j = 0; j < 4; j++)
          Mt[(size_t)(r + j) * 1024 + c] = f2bf(acc[mi][ni][j] * 0.03125f);
      }
    }
  } else {
    const int l = bx - 64;              // 0..8191
    size_t i = ((size_t)l * 256 + t) * 4;
    float4v v = *(const float4v*)(X + i);
    u16x4 o;
    o.x = f2bf(v.x); o.y = f2bf(v.y); o.z = f2bf(v.z); o.w = f2bf(v.w);
    *(u16x4*)(Xb + i) = o;
  }
}

// ---------------- Q' = X Mt^T  and  V (transposed) ----------------
// 1024 blocks at 4/CU (one resident round). XCD-chunked rows.
__global__ __launch_bounds__(256, 4) void kqkv(const u16* __restrict__ Xb,
                                               const u16* __restrict__ Mt,
                                               const u16* __restrict__ Wvt,
                                               u16* __restrict__ Qb,
                                               u16* __restrict__ Vt) {
  __shared__ __align__(16) u16 As[128 * 64];
  __shared__ __align__(16) u16 Bs[128 * 64];
  const f32x4 z4 = {0.f, 0.f, 0.f, 0.f};
  f32x4 acc[4][4];
#pragma unroll
  for (int i = 0; i < 4; i++)
#pragma unroll
    for (int j = 0; j < 4; j++) acc[i][j] = z4;

  const int l = blockIdx.x;
  const int xcd = l & 7, idx = l >> 3;     // idx 0..127
  const int cz = idx >> 3, rloc = idx & 7; // cz 0..15 outer, row inner
  const int rowTile = xcd * 8 + rloc;      // 0..63
  const int z = cz >> 3, colTile = cz & 7; // z 0..1, col 0..7

  const int rowBase = rowTile * 128, colBase = colTile * 128;
  const u16* Bt = z ? Wvt : Mt;
  gemm64(Xb, Bt, 1024, 1024, rowBase, colBase, 16, As, Bs, acc);

  const int t = threadIdx.x, wid = t >> 6, lane = t & 63;
  const int wm = wid >> 1, wn = wid & 1;
  const int r0 = rowBase + wm * 64 + ((lane >> 4) * 4);
  const int c0 = colBase + wn * 64 + (lane & 15);
  if (z == 0) {
#pragma unroll
    for (int mi = 0; mi < 4; mi++) {
      int r = r0 + mi * 16;
#pragma unroll
      for (int ni = 0; ni < 4; ni++) {
        int c = c0 + ni * 16;
#pragma unroll
        for (int j = 0; j < 4; j++)
          Qb[(size_t)(r + j) * 1024 + c] = f2bf(acc[mi][ni][j]);
      }
    }
  } else {
#pragma unroll
    for (int mi = 0; mi < 4; mi++) {
      int s0r = r0 + mi * 16;           // global row (= b*2048 + s)
      int bb = s0r >> 11, sl = s0r & 2047;
#pragma unroll
      for (int ni = 0; ni < 4; ni++) {
        int d = c0 + ni * 16;
        u16x4 pk;
        pk.x = f2bf(acc[mi][ni][0]);
        pk.y = f2bf(acc[mi][ni][1]);
        pk.z = f2bf(acc[mi][ni][2]);
        pk.w = f2bf(acc[mi][ni][3]);
        *(u16x4*)(Vt + ((size_t)bb * 1024 + d) * 2048 + sl) = pk;
      }
    }
  }
}

// -------- scores = Q' X^T (already /32 via Mt), lower-tri, fp16 out --------
__global__ __launch_bounds__(256, 3) void kscores(const u16* __restrict__ Q,
                                                  const u16* __restrict__ Xb,
                                                  u16* __restrict__ Sch) {
  const int x = blockIdx.x, b = blockIdx.y;
  const int xcd = x & 7, idx = x >> 3;   // idx 0..16
  const int tid = xcd * 17 + idx;        // 0..135
  int tr = (int)((sqrtf(8.f * tid + 1.f) - 1.f) * 0.5f);
  while ((tr + 1) * (tr + 2) / 2 <= tid) ++tr;
  while (tr * (tr + 1) / 2 > tid) --tr;
  const int tc = tid - tr * (tr + 1) / 2;

  __shared__ __align__(16) u16 As[128 * 64];
  __shared__ __align__(16) u16 Bs[128 * 64];
  const f32x4 z4 = {0.f, 0.f, 0.f, 0.f};
  f32x4 acc[4][4];
#pragma unroll
  for (int i = 0; i < 4; i++)
#pragma unroll
    for (int j = 0; j < 4; j++) acc[i][j] = z4;

  const u16* Qp = Q + (size_t)b * 2048 * 1024;
  const u16* Kp = Xb + (size_t)b * 2048 * 1024;   // B-panel is X itself
  gemm64(Qp, Kp, 1024, 1024, tr * 128, tc * 128, 16, As, Bs, acc);

  u16* S = Sch + (size_t)b * 2048 * 2048;
  const int t = threadIdx.x, wid = t >> 6, lane = t & 63;
  const int wm = wid >> 1, wn = wid & 1;
  const int r0 = tr * 128 + wm * 64 + ((lane >> 4) * 4);
  const int c0 = tc * 128 + wn * 64 + (lane & 15);
#pragma unroll
  for (int mi = 0; mi < 4; mi++) {
    int r = r0 + mi * 16;
#pragma unroll
    for (int ni = 0; ni < 4; ni++) {
      int c = c0 + ni * 16;
#pragma unroll
      for (int j = 0; j < 4; j++)
        S[(size_t)(r + j) * 2048 + c] = f2h(acc[mi][ni][j]);
    }
  }
}

// ---------------- row softmax (register-resident, nceil-bounded) ------------
__global__ __launch_bounds__(256) void ksoftmax(const u16* __restrict__ Sch,
                                                u16* __restrict__ P) {
  const int i = blockIdx.x, b = blockIdx.y;
  const int t = threadIdx.x, lane = t & 63, wid = t >> 6;
  const int nceil = ((i >> 7) + 1) << 7;
  __shared__ float red[4];

  const size_t rowoff = ((size_t)b * 2048 + i) * 2048 + t * 8;
  const int base = t * 8;
  short8 raw = {0, 0, 0, 0, 0, 0, 0, 0};
  if (base < nceil) raw = *(const short8*)(Sch + rowoff);
  float v[8];
#pragma unroll
  for (int k = 0; k < 8; ++k)
    v[k] = (base + k <= i) ? h2f((u16)raw[k]) : -3.0e38f;

  float lm = v[0];
#pragma unroll
  for (int k = 1; k < 8; ++k) lm = fmaxf(lm, v[k]);
#pragma unroll
  for (int o = 32; o > 0; o >>= 1) lm = fmaxf(lm, __shfl_down(lm, o));
  if (lane == 0) red[wid] = lm;
  __syncthreads();
  const float m = fmaxf(fmaxf(red[0], red[1]), fmaxf(red[2], red[3]));
  __syncthreads();  // everyone has m before red[] is reused

  float e[8], ls = 0.f;
#pragma unroll
  for (int k = 0; k < 8; ++k) {
    e[k] = __expf(fmaxf(v[k] - m, -88.f));
    ls += e[k];
  }
#pragma unroll
  for (int o = 32; o > 0; o >>= 1) ls += __shfl_down(ls, o);
  if (lane == 0) red[wid] = ls;
  __syncthreads();
  const float inv = 1.f / (red[0] + red[1] + red[2] + red[3]);

  if (base < nceil) {
    short8 out;
#pragma unroll
    for (int k = 0; k < 8; ++k) out[k] = (short)f2bf(e[k] * inv);
    *(short8*)(P + rowoff) = out;
  }
}

// ---------------- context = P V  (K-loop truncated causally) ----------------
__global__ __launch_bounds__(256, 3) void kpv(const u16* __restrict__ P,
                                              const u16* __restrict__ Vt,
                                              float* __restrict__ Out) {
  const int x = blockIdx.x, b = blockIdx.y;
  const int xcd = x & 7, idx = x >> 3;       // idx 0..15
  const int tr = (idx & 1) ? (15 - xcd) : xcd;
  const int col = idx >> 1;                  // 0..7

  __shared__ __align__(16) u16 As[128 * 64];
  __shared__ __align__(16) u16 Bs[128 * 64];
  const f32x4 z4 = {0.f, 0.f, 0.f, 0.f};
  f32x4 acc[4][4];
#pragma unroll
  for (int i = 0; i < 4; i++)
#pragma unroll
    for (int j = 0; j < 4; j++) acc[i][j] = z4;

  const u16* Pp = P + (size_t)b * 2048 * 2048;
  const u16* Vp = Vt + (size_t)b * 1024 * 2048;
  gemm64(Pp, Vp, 2048, 2048, tr * 128, col * 128, (tr + 1) * 2, As, Bs, acc);

  float* Ob = Out + (size_t)b * 2048 * 1024;
  const int t = threadIdx.x, wid = t >> 6, lane = t & 63;
  const int wm = wid >> 1, wn = wid & 1;
  const int r0 = tr * 128 + wm * 64 + ((lane >> 4) * 4);
  const int c0 = col * 128 + wn * 64 + (lane & 15);
#pragma unroll
  for (int mi = 0; mi < 4; mi++) {
    int r = r0 + mi * 16;
#pragma unroll
    for (int ni = 0; ni < 4; ni++) {
      int c = c0 + ni * 16;
#pragma unroll
      for (int j = 0; j < 4; j++)
        Ob[(size_t)(r + j) * 1024 + c] = acc[mi][ni][j];
    }
  }
}

extern "C" void kernel_launch(void* const* d_in, const int* in_sizes, int n_in,
                              void* d_out, int out_size, void* d_ws,
                              size_t ws_size, hipStream_t stream) {
  const float* X = (const float*)d_in[0];
  const float* Wq = (const float*)d_in[1];
  const float* Wk = (const float*)d_in[2];
  const float* Wv = (const float*)d_in[3];
  float* Out = (float*)d_out;

  char* ws = (char*)d_ws;
  u16* Xb  = (u16*)(ws);                    // 16 MB  bf16 X
  u16* Wvt = (u16*)(ws + 16777216);         //  2 MB  bf16 Wv^T
  u16* Mt  = (u16*)(ws + 18874368);         //  2 MB  bf16 (Wk Wq^T)/32
  u16* Qb  = (u16*)(ws + 20971520);         // 16 MB  Q' = X Mt^T
  u16* Vt  = (u16*)(ws + 37748736);         // 16 MB  V transposed per batch
  u16* Sch = (u16*)(ws + 54525952);         // 32 MB  fp16 scores
  u16* P   = (u16*)(ws + 88080384);         // 32 MB  bf16 probs
  u16* Wqb = (u16*)(ws + 121634816);        //  2 MB  bf16 Wq [E,D]
  u16* Wkb = (u16*)(ws + 123731968);        //  2 MB  bf16 Wk [E,D]

  kconvW<<<3072, 256, 0, stream>>>(Wq, Wk, Wv, Wqb, Wkb, Wvt);
  kconvX<<<8256, 256, 0, stream>>>(X, Wqb, Wkb, Xb, Mt);
  kqkv<<<1024, 256, 0, stream>>>(Xb, Mt, Wvt, Qb, Vt);
  kscores<<<dim3(136, 4), 256, 0, stream>>>(Qb, Xb, Sch);
  ksoftmax<<<dim3(2048, 4), 256, 0, stream>>>(Sch, P);
  kpv<<<dim3(128, 4), 256, 0, stream>>>(P, Vt, Out);
}

// Round 19
// 139.947 us; speedup vs baseline: 1.0327x; 1.0006x over previous
//
#include <hip/hip_runtime.h>
#include <hip/hip_fp16.h>

typedef unsigned short u16;
typedef __attribute__((ext_vector_type(8))) short short8;
typedef __attribute__((ext_vector_type(4))) float f32x4;
typedef __attribute__((ext_vector_type(4))) unsigned short u16x4;
typedef __attribute__((ext_vector_type(4))) float float4v;

__device__ __forceinline__ u16 f2bf(float f) {
  union { float f; unsigned u; } v; v.f = f;
  unsigned r = v.u + 0x7FFFu + ((v.u >> 16) & 1u);
  return (u16)(r >> 16);
}

__device__ __forceinline__ u16 f2h(float f) {
  __half h = __float2half(f);
  return *reinterpret_cast<u16*>(&h);
}

__device__ __forceinline__ float h2f(u16 b) {
  __half_raw hr; hr.x = b;
  return __half2float(__half(hr));
}

__device__ __forceinline__ void gload16(const void* g, void* l) {
  __builtin_amdgcn_global_load_lds(
      (const __attribute__((address_space(1))) unsigned int*)g,
      (__attribute__((address_space(3))) unsigned int*)l, 16, 0, 0);
}

// ---------------- stage 1: weight conversions (pure BW, ~3 us) ----------------
// bx<1024: Wq fp32->bf16 linear.  <2048: Wk linear.  else: Wv transpose.
__global__ __launch_bounds__(256) void kconvW(const float* __restrict__ Wq,
                                              const float* __restrict__ Wk,
                                              const float* __restrict__ Wv,
                                              u16* __restrict__ Wqb,
                                              u16* __restrict__ Wkb,
                                              u16* __restrict__ Wvt) {
  __shared__ float tile[32][33];
  const int bx = blockIdx.x, t = threadIdx.x;
  if (bx < 2048) {
    const float* W = bx < 1024 ? Wq : Wk;
    u16* O = bx < 1024 ? Wqb : Wkb;
    size_t i = ((size_t)(bx & 1023) * 256 + t) * 4;
    float4v v = *(const float4v*)(W + i);
    u16x4 o;
    o.x = f2bf(v.x); o.y = f2bf(v.y); o.z = f2bf(v.z); o.w = f2bf(v.w);
    *(u16x4*)(O + i) = o;
  } else {
    const int rem = bx - 2048;          // 32x32 tiles of Wv
    const int n0 = (rem & 31) * 32, k0 = (rem >> 5) * 32;
    const int tx = t & 31, ty = t >> 5; // 32 x 8
#pragma unroll
    for (int r = 0; r < 32; r += 8)
      tile[ty + r][tx] = Wv[(size_t)(k0 + ty + r) * 1024 + n0 + tx];
    __syncthreads();
#pragma unroll
    for (int r = 0; r < 32; r += 8)
      Wvt[(size_t)(n0 + ty + r) * 1024 + k0 + tx] = f2bf(tile[tx][ty + r]);
  }
}

// ---------------- GEMM core: BK=64, both-sides XOR swizzle ----------------
__device__ __forceinline__ void stage64(const u16* __restrict__ pan, int ld,
                                        int k0, u16* dst, int t) {
  const int rb = t >> 3;                     // 0..31
  const int sw = ((t & 7) ^ (rb & 7)) * 8;   // pre-swizzled source slot
  const int ds = (t & 7) * 8;                // linear LDS slot
#pragma unroll
  for (int j = 0; j < 4; ++j) {
    const int row = j * 32 + rb;
    gload16(pan + (size_t)row * ld + k0 + sw, dst + row * 64 + ds);
  }
}

__device__ __forceinline__ void gemm64(const u16* __restrict__ A,
                                       const u16* __restrict__ B,
                                       int lda, int ldb,
                                       int rowBase, int colBase, int kIters,
                                       u16* As, u16* Bs, f32x4 acc[4][4]) {
  const int t = threadIdx.x;
  const int wid = t >> 6, lane = t & 63;
  const int wm = wid >> 1, wn = wid & 1;
  const int l15 = lane & 15;
  const int sw = l15 & 7;
  const int sl = lane >> 4;                  // 0..3
  const int s0 = ((sl    ) ^ sw) * 8;        // k 0..31 slot (u16 offset)
  const int s1 = ((sl + 4) ^ sw) * 8;        // k 32..63 slot
  const u16* ga = A + (size_t)rowBase * lda;
  const u16* gb = B + (size_t)colBase * ldb;

  for (int kt = 0; kt < kIters; ++kt) {
    const int k0 = kt * 64;
    stage64(ga, lda, k0, As, t);
    stage64(gb, ldb, k0, Bs, t);
    __syncthreads();
#pragma unroll
    for (int h = 0; h < 2; ++h) {
      const int so = h ? s1 : s0;
      short8 a[4], b[4];
#pragma unroll
      for (int mi = 0; mi < 4; mi++)
        a[mi] = *(const short8*)(As + (wm * 64 + mi * 16 + l15) * 64 + so);
#pragma unroll
      for (int ni = 0; ni < 4; ni++)
        b[ni] = *(const short8*)(Bs + (wn * 64 + ni * 16 + l15) * 64 + so);
#pragma unroll
      for (int mi = 0; mi < 4; mi++)
#pragma unroll
        for (int ni = 0; ni < 4; ni++)
          acc[mi][ni] = __builtin_amdgcn_mfma_f32_16x16x32_bf16(
              a[mi], b[ni], acc[mi][ni], 0, 0, 0);
    }
    __syncthreads();
  }
}

// ---------------- stage 2: X convert + Mt GEMM (overlapped) ----------------
// bx<64: Mt = (Wk Wq^T)/32 from bf16 via gload_lds (runs ~10us, hidden under
// the 8192 X-convert blocks).  else: X fp32->bf16 linear.
__global__ __launch_bounds__(256) void kconvX(const float* __restrict__ X,
                                              const u16* __restrict__ Wqb,
                                              const u16* __restrict__ Wkb,
                                              u16* __restrict__ Xb,
                                              u16* __restrict__ Mt) {
  __shared__ __align__(16) u16 As[128 * 64];
  __shared__ __align__(16) u16 Bs[128 * 64];
  const int bx = blockIdx.x, t = threadIdx.x;
  if (bx < 64) {
    const f32x4 z4 = {0.f, 0.f, 0.f, 0.f};
    f32x4 acc[4][4];
#pragma unroll
    for (int i = 0; i < 4; i++)
#pragma unroll
      for (int j = 0; j < 4; j++) acc[i][j] = z4;

    const int rowBase = (bx >> 3) * 128, colBase = (bx & 7) * 128;
    gemm64(Wkb, Wqb, 1024, 1024, rowBase, colBase, 16, As, Bs, acc);

    const int wid = t >> 6, lane = t & 63;
    const int wm = wid >> 1, wn = wid & 1;
    const int r0 = rowBase + wm * 64 + ((lane >> 4) * 4);
    const int c0 = colBase + wn * 64 + (lane & 15);
#pragma unroll
    for (int mi = 0; mi < 4; mi++) {
      int r = r0 + mi * 16;
#pragma unroll
      for (int ni = 0; ni < 4; ni++) {
        int c = c0 + ni * 16;
#pragma unroll
        for (int j = 0; j < 4; j++)
          Mt[(size_t)(r + j) * 1024 + c] = f2bf(acc[mi][ni][j] * 0.03125f);
      }
    }
  } else {
    const int l = bx - 64;              // 0..8191
    size_t i = ((size_t)l * 256 + t) * 4;
    float4v v = *(const float4v*)(X + i);
    u16x4 o;
    o.x = f2bf(v.x); o.y = f2bf(v.y); o.z = f2bf(v.z); o.w = f2bf(v.w);
    *(u16x4*)(Xb + i) = o;
  }
}

// ---------------- Q' = X Mt^T  and  V (transposed) ----------------
// 1024 blocks at 4/CU (one resident round). XCD-chunked rows.
__global__ __launch_bounds__(256, 4) void kqkv(const u16* __restrict__ Xb,
                                               const u16* __restrict__ Mt,
                                               const u16* __restrict__ Wvt,
                                               u16* __restrict__ Qb,
                                               u16* __restrict__ Vt) {
  __shared__ __align__(16) u16 As[128 * 64];
  __shared__ __align__(16) u16 Bs[128 * 64];
  const f32x4 z4 = {0.f, 0.f, 0.f, 0.f};
  f32x4 acc[4][4];
#pragma unroll
  for (int i = 0; i < 4; i++)
#pragma unroll
    for (int j = 0; j < 4; j++) acc[i][j] = z4;

  const int l = blockIdx.x;
  const int xcd = l & 7, idx = l >> 3;     // idx 0..127
  const int cz = idx >> 3, rloc = idx & 7; // cz 0..15 outer, row inner
  const int rowTile = xcd * 8 + rloc;      // 0..63
  const int z = cz >> 3, colTile = cz & 7; // z 0..1, col 0..7

  const int rowBase = rowTile * 128, colBase = colTile * 128;
  const u16* Bt = z ? Wvt : Mt;
  gemm64(Xb, Bt, 1024, 1024, rowBase, colBase, 16, As, Bs, acc);

  const int t = threadIdx.x, wid = t >> 6, lane = t & 63;
  const int wm = wid >> 1, wn = wid & 1;
  const int r0 = rowBase + wm * 64 + ((lane >> 4) * 4);
  const int c0 = colBase + wn * 64 + (lane & 15);
  if (z == 0) {
#pragma unroll
    for (int mi = 0; mi < 4; mi++) {
      int r = r0 + mi * 16;
#pragma unroll
      for (int ni = 0; ni < 4; ni++) {
        int c = c0 + ni * 16;
#pragma unroll
        for (int j = 0; j < 4; j++)
          Qb[(size_t)(r + j) * 1024 + c] = f2bf(acc[mi][ni][j]);
      }
    }
  } else {
#pragma unroll
    for (int mi = 0; mi < 4; mi++) {
      int s0r = r0 + mi * 16;           // global row (= b*2048 + s)
      int bb = s0r >> 11, sl = s0r & 2047;
#pragma unroll
      for (int ni = 0; ni < 4; ni++) {
        int d = c0 + ni * 16;
        u16x4 pk;
        pk.x = f2bf(acc[mi][ni][0]);
        pk.y = f2bf(acc[mi][ni][1]);
        pk.z = f2bf(acc[mi][ni][2]);
        pk.w = f2bf(acc[mi][ni][3]);
        *(u16x4*)(Vt + ((size_t)bb * 1024 + d) * 2048 + sl) = pk;
      }
    }
  }
}

// -------- scores = Q' X^T (already /32 via Mt), lower-tri, fp16 out --------
__global__ __launch_bounds__(256, 3) void kscores(const u16* __restrict__ Q,
                                                  const u16* __restrict__ Xb,
                                                  u16* __restrict__ Sch) {
  const int x = blockIdx.x, b = blockIdx.y;
  const int xcd = x & 7, idx = x >> 3;   // idx 0..16
  const int tid = xcd * 17 + idx;        // 0..135
  int tr = (int)((sqrtf(8.f * tid + 1.f) - 1.f) * 0.5f);
  while ((tr + 1) * (tr + 2) / 2 <= tid) ++tr;
  while (tr * (tr + 1) / 2 > tid) --tr;
  const int tc = tid - tr * (tr + 1) / 2;

  __shared__ __align__(16) u16 As[128 * 64];
  __shared__ __align__(16) u16 Bs[128 * 64];
  const f32x4 z4 = {0.f, 0.f, 0.f, 0.f};
  f32x4 acc[4][4];
#pragma unroll
  for (int i = 0; i < 4; i++)
#pragma unroll
    for (int j = 0; j < 4; j++) acc[i][j] = z4;

  const u16* Qp = Q + (size_t)b * 2048 * 1024;
  const u16* Kp = Xb + (size_t)b * 2048 * 1024;   // B-panel is X itself
  gemm64(Qp, Kp, 1024, 1024, tr * 128, tc * 128, 16, As, Bs, acc);

  u16* S = Sch + (size_t)b * 2048 * 2048;
  const int t = threadIdx.x, wid = t >> 6, lane = t & 63;
  const int wm = wid >> 1, wn = wid & 1;
  const int r0 = tr * 128 + wm * 64 + ((lane >> 4) * 4);
  const int c0 = tc * 128 + wn * 64 + (lane & 15);
#pragma unroll
  for (int mi = 0; mi < 4; mi++) {
    int r = r0 + mi * 16;
#pragma unroll
    for (int ni = 0; ni < 4; ni++) {
      int c = c0 + ni * 16;
#pragma unroll
      for (int j = 0; j < 4; j++)
        S[(size_t)(r + j) * 2048 + c] = f2h(acc[mi][ni][j]);
    }
  }
}

// ---------------- row softmax (register-resident, nceil-bounded) ------------
__global__ __launch_bounds__(256) void ksoftmax(const u16* __restrict__ Sch,
                                                u16* __restrict__ P) {
  const int i = blockIdx.x, b = blockIdx.y;
  const int t = threadIdx.x, lane = t & 63, wid = t >> 6;
  const int nceil = ((i >> 7) + 1) << 7;
  __shared__ float red[4];

  const size_t rowoff = ((size_t)b * 2048 + i) * 2048 + t * 8;
  const int base = t * 8;
  short8 raw = {0, 0, 0, 0, 0, 0, 0, 0};
  if (base < nceil) raw = *(const short8*)(Sch + rowoff);
  float v[8];
#pragma unroll
  for (int k = 0; k < 8; ++k)
    v[k] = (base + k <= i) ? h2f((u16)raw[k]) : -3.0e38f;

  float lm = v[0];
#pragma unroll
  for (int k = 1; k < 8; ++k) lm = fmaxf(lm, v[k]);
#pragma unroll
  for (int o = 32; o > 0; o >>= 1) lm = fmaxf(lm, __shfl_down(lm, o));
  if (lane == 0) red[wid] = lm;
  __syncthreads();
  const float m = fmaxf(fmaxf(red[0], red[1]), fmaxf(red[2], red[3]));
  __syncthreads();  // everyone has m before red[] is reused

  float e[8], ls = 0.f;
#pragma unroll
  for (int k = 0; k < 8; ++k) {
    e[k] = __expf(fmaxf(v[k] - m, -88.f));
    ls += e[k];
  }
#pragma unroll
  for (int o = 32; o > 0; o >>= 1) ls += __shfl_down(ls, o);
  if (lane == 0) red[wid] = ls;
  __syncthreads();
  const float inv = 1.f / (red[0] + red[1] + red[2] + red[3]);

  if (base < nceil) {
    short8 out;
#pragma unroll
    for (int k = 0; k < 8; ++k) out[k] = (short)f2bf(e[k] * inv);
    *(short8*)(P + rowoff) = out;
  }
}

// ---------------- context = P V  (K-loop truncated causally) ----------------
// Balance fix: with grid (128,4), a CU receives per-XCD sequence slots s and
// s+32, i.e. blocks (b,idx) and (b+2,idx). Flip the tr choice on the batch
// half (b>>1) so those two blocks carry tr and 15-tr -> every CU gets exactly
// 34 k-iters ((tr+1+16-tr)*2) instead of 4..64.
__global__ __launch_bounds__(256, 3) void kpv(const u16* __restrict__ P,
                                              const u16* __restrict__ Vt,
                                              float* __restrict__ Out) {
  const int x = blockIdx.x, b = blockIdx.y;
  const int xcd = x & 7, idx = x >> 3;       // idx 0..15
  const int tr = ((idx & 1) ^ (b >> 1)) ? (15 - xcd) : xcd;
  const int col = idx >> 1;                  // 0..7

  __shared__ __align__(16) u16 As[128 * 64];
  __shared__ __align__(16) u16 Bs[128 * 64];
  const f32x4 z4 = {0.f, 0.f, 0.f, 0.f};
  f32x4 acc[4][4];
#pragma unroll
  for (int i = 0; i < 4; i++)
#pragma unroll
    for (int j = 0; j < 4; j++) acc[i][j] = z4;

  const u16* Pp = P + (size_t)b * 2048 * 2048;
  const u16* Vp = Vt + (size_t)b * 1024 * 2048;
  gemm64(Pp, Vp, 2048, 2048, tr * 128, col * 128, (tr + 1) * 2, As, Bs, acc);

  float* Ob = Out + (size_t)b * 2048 * 1024;
  const int t = threadIdx.x, wid = t >> 6, lane = t & 63;
  const int wm = wid >> 1, wn = wid & 1;
  const int r0 = tr * 128 + wm * 64 + ((lane >> 4) * 4);
  const int c0 = col * 128 + wn * 64 + (lane & 15);
#pragma unroll
  for (int mi = 0; mi < 4; mi++) {
    int r = r0 + mi * 16;
#pragma unroll
    for (int ni = 0; ni < 4; ni++) {
      int c = c0 + ni * 16;
#pragma unroll
      for (int j = 0; j < 4; j++)
        Ob[(size_t)(r + j) * 1024 + c] = acc[mi][ni][j];
    }
  }
}

extern "C" void kernel_launch(void* const* d_in, const int* in_sizes, int n_in,
                              void* d_out, int out_size, void* d_ws,
                              size_t ws_size, hipStream_t stream) {
  const float* X = (const float*)d_in[0];
  const float* Wq = (const float*)d_in[1];
  const float* Wk = (const float*)d_in[2];
  const float* Wv = (const float*)d_in[3];
  float* Out = (float*)d_out;

  char* ws = (char*)d_ws;
  u16* Xb  = (u16*)(ws);                    // 16 MB  bf16 X
  u16* Wvt = (u16*)(ws + 16777216);         //  2 MB  bf16 Wv^T
  u16* Mt  = (u16*)(ws + 18874368);         //  2 MB  bf16 (Wk Wq^T)/32
  u16* Qb  = (u16*)(ws + 20971520);         // 16 MB  Q' = X Mt^T
  u16* Vt  = (u16*)(ws + 37748736);         // 16 MB  V transposed per batch
  u16* Sch = (u16*)(ws + 54525952);         // 32 MB  fp16 scores
  u16* P   = (u16*)(ws + 88080384);         // 32 MB  bf16 probs
  u16* Wqb = (u16*)(ws + 121634816);        //  2 MB  bf16 Wq [E,D]
  u16* Wkb = (u16*)(ws + 123731968);        //  2 MB  bf16 Wk [E,D]

  kconvW<<<3072, 256, 0, stream>>>(Wq, Wk, Wv, Wqb, Wkb, Wvt);
  kconvX<<<8256, 256, 0, stream>>>(X, Wqb, Wkb, Xb, Mt);
  kqkv<<<1024, 256, 0, stream>>>(Xb, Mt, Wvt, Qb, Vt);
  kscores<<<dim3(136, 4), 256, 0, stream>>>(Qb, Xb, Sch);
  ksoftmax<<<dim3(2048, 4), 256, 0, stream>>>(Sch, P);
  kpv<<<dim3(128, 4), 256, 0, stream>>>(P, Vt, Out);
}